// Round 1
// baseline (120.301 us; speedup 1.0000x reference)
//
#include <hip/hip_runtime.h>
#include <stdint.h>

typedef __attribute__((ext_vector_type(8))) __bf16 bf16x8;
typedef __attribute__((ext_vector_type(4))) float f32x4;

// Selected upper-tri circular-adjacency pairs (r,c), row-major triu order. K=64.
__device__ const unsigned char dR[64] = {
  0,0,0,0,0,0,0,
  1,1,1,1,1,1,
  2,2,2,2,2,
  3,3,3,3,
  4,4,4,4,
  5,5,5,5,
  6,6,6,6,
  7,7,7,7,
  8,8,8,8,
  9,9,9,9,
  10,10,10,10,
  11,11,11,11,
  12,12,12,12,
  13,13,13,
  14,14,
  15};
__device__ const unsigned char dC[64] = {
  0,1,2,3,13,14,15,
  1,2,3,4,14,15,
  2,3,4,5,15,
  3,4,5,6,
  4,5,6,7,
  5,6,7,8,
  6,7,8,9,
  7,8,9,10,
  8,9,10,11,
  9,10,11,12,
  10,11,12,13,
  11,12,13,14,
  12,13,14,15,
  13,14,15,
  14,15,
  15};

__device__ __forceinline__ unsigned short f2bf(float x){
  unsigned u = __builtin_bit_cast(unsigned, x);
  return (unsigned short)((u + 0x7FFFu + ((u >> 16) & 1u)) >> 16);
}

__device__ __forceinline__ void gl16(const void* g, void* l){
  __builtin_amdgcn_global_load_lds((const __attribute__((address_space(1))) unsigned int*)g,
                                   (__attribute__((address_space(3))) unsigned int*)l,
                                   16, 0, 0);
}

// fp32 -> bf16 weight conversion into workspace (2.62 MB total)
__global__ void conv_w_kernel(const float* __restrict__ w1, const float* __restrict__ w2,
                              unsigned short* __restrict__ o1, unsigned short* __restrict__ o2){
  int i = blockIdx.x * 256 + threadIdx.x;
  if (i < 262144){                       // W1: 512*2048 = 262144 float4 groups
    float4 v = ((const float4*)w1)[i];
    ushort4 pk; pk.x=f2bf(v.x); pk.y=f2bf(v.y); pk.z=f2bf(v.z); pk.w=f2bf(v.w);
    ((ushort4*)o1)[i] = pk;
  } else {
    int j = i - 262144;
    if (j < 65536){                      // W2: 512*512
      float4 v = ((const float4*)w2)[j];
      ushort4 pk; pk.x=f2bf(v.x); pk.y=f2bf(v.y); pk.z=f2bf(v.z); pk.w=f2bf(v.w);
      ((ushort4*)o2)[j] = pk;
    }
  }
}

// Fused: gather(roll+triu-select) -> GEMM1(+bias,leaky) -> GEMM2(+bias,leaky) -> mean(o) -> [B,H,T]
// Block: (b, 16-t tile). 512 threads = 8 waves; each wave owns 64 cols of H in phase 1,
// 2x32 cols in phase 2. LDS exactly 64 KiB -> 2 blocks/CU.
__global__ __launch_bounds__(512, 4)
void fused_kernel(const float* __restrict__ x,
                  const float* __restrict__ b1v,
                  const float* __restrict__ b2v,
                  const unsigned short* __restrict__ w1b,
                  const unsigned short* __restrict__ w2b,
                  float* __restrict__ out)
{
  __shared__ char lds[65536];
  // LDS map: [0,32768)  phase1 W1^T tile [512][32] bf16 (pitch 64B)
  //          [32768,38912) phase1 gather tiles [o][kb4][t16][ke8] bf16
  //          [0,49152)  A1 [o][t16][h512] bf16, XOR-swizzled  (written AFTER phase1 reads)
  //          [49152,65536) phase2 W2^T tile [256][32] bf16
  const int bid = blockIdx.x;
  const int wg  = ((bid & 7) << 6) | (bid >> 3);   // bijective XCD swizzle (512 % 8 == 0)
  const int b   = wg >> 4;
  const int t0  = (wg & 15) << 4;

  const int tid  = threadIdx.x;
  const int w    = tid >> 6;
  const int lane = tid & 63;
  const int q    = lane >> 4;
  const int lr   = lane & 15;

  // ---- gather staging role: thread = (klocal 0..31, t 0..15) ----
  const int klA = tid >> 4;
  const int tA  = tid & 15;
  int poff[2][3];
#pragma unroll
  for (int par = 0; par < 2; ++par){
    const int k = par * 32 + klA;
    const int r = dR[k], c = dC[k];
#pragma unroll
    for (int o = 0; o < 3; ++o){
      const int v  = o - 1;                       // offset value in {-1,0,1}; mean is order-free
      const int io = (r - v) & 15;
      const int jo = (c - v) & 15;
      poff[par][o] = ((io << 4) | jo) << 8;       // element offset inside [16][16][256] slab
    }
  }
  const float* xb = x + (((long)b * 32) << 16) + t0 + tA;
  char* const agbase = lds + 32768 + ((klA >> 3) << 8) + (tA << 4) + ((klA & 7) << 1);

  f32x4 acc[3][4];
#pragma unroll
  for (int o = 0; o < 3; ++o)
#pragma unroll
    for (int ct = 0; ct < 4; ++ct)
      acc[o][ct] = f32x4{0.f, 0.f, 0.f, 0.f};

  // ================= Phase 1: A1 = leaky(X @ W1^T + b1), K = 2048 =================
  for (int ks = 0; ks < 64; ++ks){
    const int d0  = ks << 5;       // global d offset (= f*64 + khalf)
    const int f   = ks >> 1;
    const int par = ks & 1;
    // stage W1^T tile [512][32] via async global->LDS (lane-linear dest matches [h][k] pitch-64 layout)
#pragma unroll
    for (int i = 0; i < 4; ++i){
      const int row = ((w * 4 + i) << 4) + (lane >> 2);
      gl16((const char*)w1b + row * 4096 + d0 * 2 + (lane & 3) * 16,
           lds + ((w * 4 + i) << 10));
    }
    // stage gathered X tiles for the 3 offsets (coalesced 64B segments over t)
    {
      const float* xf = xb + (f << 16);
#pragma unroll
      for (int o = 0; o < 3; ++o){
        const float xv = xf[poff[par][o]];
        *(unsigned short*)(agbase + (o << 11)) = f2bf(xv);
      }
    }
    __syncthreads();
    bf16x8 af[3];
#pragma unroll
    for (int o = 0; o < 3; ++o)   // A-frag: X[t0+(lr)][d0 + 8q + e], one ds_read_b128
      af[o] = *(const bf16x8*)(lds + 32768 + (o << 11) + (q << 8) + (lr << 4));
#pragma unroll
    for (int ct = 0; ct < 4; ++ct){
      const bf16x8 bfr = *(const bf16x8*)(lds + (((w << 6) + (ct << 4) + lr) << 6) + (q << 4));
#pragma unroll
      for (int o = 0; o < 3; ++o)
        acc[o][ct] = __builtin_amdgcn_mfma_f32_16x16x32_bf16(af[o], bfr, acc[o][ct], 0, 0, 0);
    }
    __syncthreads();
  }

  // epilogue 1: bias + leaky -> A1 bf16 in LDS (aliases staging region; safe post-barrier)
#pragma unroll
  for (int o = 0; o < 3; ++o)
#pragma unroll
    for (int ct = 0; ct < 4; ++ct){
      const int col = (w << 6) + (ct << 4) + lr;
      const float bb = b1v[col];
#pragma unroll
      for (int r = 0; r < 4; ++r){
        float vv = acc[o][ct][r] + bb;
        vv = vv > 0.f ? vv : 0.01f * vv;
        const int trow = (q << 2) + r;           // D row = 4*(lane>>4)+reg  (verified CDNA4 layout)
        const int byt  = (((o << 4) + trow) << 10) + (col << 1);
        *(unsigned short*)(lds + (byt ^ ((trow & 7) << 4))) = f2bf(vv);
      }
    }
  __syncthreads();

  // ================= Phase 2: out = mean_o leaky(A1 @ W2^T + b2), K = 512 =================
  f32x4 macc[4];
#pragma unroll
  for (int i = 0; i < 4; ++i) macc[i] = f32x4{0.f,0.f,0.f,0.f};

#pragma unroll 1
  for (int p = 0; p < 2; ++p){                   // two 256-col halves of H (LDS budget)
    f32x4 s2[3][2];
#pragma unroll
    for (int o = 0; o < 3; ++o){ s2[o][0] = f32x4{0.f,0.f,0.f,0.f}; s2[o][1] = f32x4{0.f,0.f,0.f,0.f}; }
    for (int ks2 = 0; ks2 < 16; ++ks2){
      const int k0 = ks2 << 5;
#pragma unroll
      for (int i = 0; i < 2; ++i){
        const int hl = ((w * 2 + i) << 4) + (lane >> 2);
        gl16((const char*)w2b + (p * 256 + hl) * 1024 + k0 * 2 + (lane & 3) * 16,
             lds + 49152 + ((w * 2 + i) << 10));
      }
      __syncthreads();
      bf16x8 a2[3];
#pragma unroll
      for (int o = 0; o < 3; ++o){               // A-frag from swizzled A1: conflict-free b128
        const int byt = (((o << 4) + lr) << 10) + ((k0 + 8 * q) << 1);
        a2[o] = *(const bf16x8*)(lds + (byt ^ ((lr & 7) << 4)));
      }
#pragma unroll
      for (int c2 = 0; c2 < 2; ++c2){
        const bf16x8 bfr = *(const bf16x8*)(lds + 49152 + (((w << 5) + (c2 << 4) + lr) << 6) + (q << 4));
#pragma unroll
        for (int o = 0; o < 3; ++o)
          s2[o][c2] = __builtin_amdgcn_mfma_f32_16x16x32_bf16(a2[o], bfr, s2[o][c2], 0, 0, 0);
      }
      __syncthreads();
    }
#pragma unroll
    for (int c2 = 0; c2 < 2; ++c2){
      const int col = (p << 8) + (w << 5) + (c2 << 4) + lr;
      const float bb = b2v[col];
#pragma unroll
      for (int o = 0; o < 3; ++o)
#pragma unroll
        for (int r = 0; r < 4; ++r){
          float vv = s2[o][c2][r] + bb;
          vv = vv > 0.f ? vv : 0.01f * vv;
          macc[(p << 1) + c2][r] += vv;
        }
    }
  }

  // store: lane float4 = 4 consecutive t for one h; wave instruction covers 16 h x 64B -> fully coalesced
#pragma unroll
  for (int ci = 0; ci < 4; ++ci){
    const int col = ((ci >> 1) << 8) + (w << 5) + ((ci & 1) << 4) + lr;
    f32x4 ov;
#pragma unroll
    for (int r = 0; r < 4; ++r) ov[r] = macc[ci][r] * (1.f / 3.f);
    *(f32x4*)(out + (((b << 9) + col) << 8) + t0 + (q << 2)) = ov;
  }
}

extern "C" void kernel_launch(void* const* d_in, const int* in_sizes, int n_in,
                              void* d_out, int out_size, void* d_ws, size_t ws_size,
                              hipStream_t stream){
  const float* x  = (const float*)d_in[0];
  const float* w1 = (const float*)d_in[1];
  const float* b1 = (const float*)d_in[2];
  const float* w2 = (const float*)d_in[3];
  const float* b2 = (const float*)d_in[4];
  unsigned short* w1b = (unsigned short*)d_ws;            // 512*2048 bf16 = 2 MiB
  unsigned short* w2b = w1b + 512 * 2048;                 // 512*512  bf16 = 0.5 MiB
  conv_w_kernel<<<1280, 256, 0, stream>>>(w1, w2, w1b, w2b);
  fused_kernel<<<512, 512, 0, stream>>>(x, b1, b2, w1b, w2b, (float*)d_out);
}